// Round 7
// baseline (739.237 us; speedup 1.0000x reference)
//
#include <hip/hip_runtime.h>

// ResidualVQ: Q=4, N_EMBED=1024, DIM=256, B=8, S=2048 (fp32).
// out = [quantized 8*2048*256][indices-as-float 4*8*2048][losses 4]
//
// Bit-structural mirror of the numpy fp32 reference (verified R4-R6, idx exact):
//   dist = fl32( fl32(a - fl32(2*m)) + b ); a,b = AVX-512 pairwise sumsq;
//   m = ascending-d single-accumulator fp32 fma chain; first-occurrence argmin;
//   STE recursion op-for-op (feeds next stage's argmin -> FROZEN).
// R7 perf: __launch_bounds__(256,4) so acc[] stays in arch VGPRs (R6's VGPR=32
// forced AGPR round-trips: VALU issue 97us vs 55us fmac floor); TM=16 halves
// per-CU ET L2 traffic; k_a folded into k_stage (same frozen sumsq).
#define QQ   4
#define NE   1024
#define DIMD 256
#define MM   16384
#define TM   16

// ws layout (float offsets):
//  ET    [QQ][DIMD][NE] @ 0          (1,048,576)
//  bK    [QQ][NE]       @ 1,048,576  (4,096)
//  resid [MM][DIMD]     @ 1,052,672  (4,194,304)
//  loss64 double[QQ]    @ 5,246,976  (8B aligned)

// numpy (AVX-512 dispatch) pairwise sum of squares of 256 contiguous f32 — FROZEN
__device__ __forceinline__ float np_sumsq_256(const float* __restrict__ v) {
  float blk[2];
  #pragma unroll
  for (int bi = 0; bi < 2; ++bi) {
    const float* p = v + bi * 128;
    float w[16];
    #pragma unroll
    for (int L = 0; L < 16; ++L) {
      float s0 = __fmul_rn(p[0 * 16 + L], p[0 * 16 + L]);
      float s1 = __fmul_rn(p[1 * 16 + L], p[1 * 16 + L]);
      float s2 = __fmul_rn(p[2 * 16 + L], p[2 * 16 + L]);
      float s3 = __fmul_rn(p[3 * 16 + L], p[3 * 16 + L]);
      float s4 = __fmul_rn(p[4 * 16 + L], p[4 * 16 + L]);
      float s5 = __fmul_rn(p[5 * 16 + L], p[5 * 16 + L]);
      float s6 = __fmul_rn(p[6 * 16 + L], p[6 * 16 + L]);
      float s7 = __fmul_rn(p[7 * 16 + L], p[7 * 16 + L]);
      w[L] = __fadd_rn(__fadd_rn(__fadd_rn(s0, s1), __fadd_rn(s2, s3)),
                       __fadd_rn(__fadd_rn(s4, s5), __fadd_rn(s6, s7)));
    }
    float u[8], t[4], r2[2];
    #pragma unroll
    for (int L = 0; L < 8; ++L) u[L] = __fadd_rn(w[L], w[L + 8]);
    #pragma unroll
    for (int L = 0; L < 4; ++L) t[L] = __fadd_rn(u[L], u[L + 4]);
    #pragma unroll
    for (int L = 0; L < 2; ++L) r2[L] = __fadd_rn(t[L], t[L + 2]);
    blk[bi] = __fadd_rn(r2[0], r2[1]);
  }
  return __fadd_rn(blk[0], blk[1]);
}

__global__ __launch_bounds__(256) void k_init(const float* __restrict__ x,
                                              float* __restrict__ resid,
                                              double* __restrict__ loss64) {
  size_t i = (size_t)blockIdx.x * blockDim.x + threadIdx.x;
  const size_t n4 = (size_t)MM * DIMD / 4;
  const float4* xs = (const float4*)x;
  float4* rd = (float4*)resid;
  for (size_t p = i; p < n4; p += (size_t)gridDim.x * blockDim.x) rd[p] = xs[p];
  if (i < QQ) loss64[i] = 0.0;
}

// wave per (qi,code): transpose codebook row into ET[d][k]
__global__ __launch_bounds__(64) void k_prep(const float* __restrict__ cb,
                                             float* __restrict__ ET) {
  int b = blockIdx.x;                 // qi*NE + k
  int qi = b >> 10, k = b & (NE - 1);
  int lane = threadIdx.x;
  const float* row = cb + ((size_t)qi * NE + k) * DIMD;
  float4 v = *(const float4*)(row + lane * 4);
  float* et = ET + (size_t)qi * DIMD * NE + k;
  int d = lane * 4;
  et[(size_t)(d + 0) * NE] = v.x;
  et[(size_t)(d + 1) * NE] = v.y;
  et[(size_t)(d + 2) * NE] = v.z;
  et[(size_t)(d + 3) * NE] = v.w;
}

__global__ __launch_bounds__(256) void k_b(const float* __restrict__ cb,
                                           float* __restrict__ bK) {
  int k = blockIdx.x * 256 + threadIdx.x;
  bK[k] = np_sumsq_256(cb + (size_t)k * DIMD);
}

// 256 threads = 4 waves; block handles TM=16 rows; wave w handles code chunk w.
// x loads wave-uniform (s_load path); a_m computed in-block (frozen sumsq).
__global__ __launch_bounds__(256, 4) void k_stage(
    const float* __restrict__ ET,      // [DIMD][NE] for qi
    const float* __restrict__ bK,      // [NE] for qi
    const float* __restrict__ cb,      // [NE][DIMD] for qi
    const float* __restrict__ resid_r, // == resid
    float* __restrict__ resid_w,       // == resid
    double* __restrict__ loss64,       // &loss64[qi]
    float* __restrict__ idx_out) {     // [MM] floats
  __shared__ float av_s[TM];
  __shared__ float candD[TM][4];
  __shared__ int   candI[TM][4];
  __shared__ int   bcode[TM];
  __shared__ double lossW[4];

  const int tid  = threadIdx.x;
  const int lane = tid & 63;
  const int wv   = tid >> 6;
  const int rowBase = blockIdx.x * TM;

  // a_m for this block's rows — FROZEN np pairwise sumsq
  if (tid < TM) av_s[tid] = np_sumsq_256(resid_r + (size_t)(rowBase + tid) * DIMD);
  __syncthreads();

  const int cbase = wv * 256 + lane * 4;   // this wave's chunk, lane's 4 codes

  float4 acc[TM];
  #pragma unroll
  for (int r = 0; r < TM; ++r) acc[r] = make_float4(0.f, 0.f, 0.f, 0.f);

  // m: single-accumulator fp32 fma chain, strictly ascending d per code — FROZEN
  for (int d0 = 0; d0 < DIMD; d0 += 4) {
    float4 e[4];
    #pragma unroll
    for (int j = 0; j < 4; ++j)
      e[j] = *(const float4*)(ET + (size_t)(d0 + j) * NE + cbase);
    // two 8-row groups to cap live scalar regs (x loads are wave-uniform -> s_load)
    #pragma unroll
    for (int g = 0; g < 2; ++g) {
      float4 xr[8];
      #pragma unroll
      for (int r = 0; r < 8; ++r)
        xr[r] = *(const float4*)(resid_r + (size_t)(rowBase + g * 8 + r) * DIMD + d0);
      #pragma unroll
      for (int j = 0; j < 4; ++j) {
        #pragma unroll
        for (int r = 0; r < 8; ++r) {
          float xv = (j == 0) ? xr[r].x : (j == 1) ? xr[r].y : (j == 2) ? xr[r].z : xr[r].w;
          float4& a = acc[g * 8 + r];
          a.x = fmaf(xv, e[j].x, a.x);
          a.y = fmaf(xv, e[j].y, a.y);
          a.z = fmaf(xv, e[j].z, a.z);
          a.w = fmaf(xv, e[j].w, a.w);
        }
      }
    }
  }

  float4 bv = *(const float4*)(bK + cbase);
  float bestD[TM];
  int bestI[TM];
  #pragma unroll
  for (int r = 0; r < TM; ++r) {
    const float av = av_s[r];
    float s[4];
    s[0] = __fadd_rn(__fsub_rn(av, __fmul_rn(2.0f, acc[r].x)), bv.x);
    s[1] = __fadd_rn(__fsub_rn(av, __fmul_rn(2.0f, acc[r].y)), bv.y);
    s[2] = __fadd_rn(__fsub_rn(av, __fmul_rn(2.0f, acc[r].z)), bv.z);
    s[3] = __fadd_rn(__fsub_rn(av, __fmul_rn(2.0f, acc[r].w)), bv.w);
    bestD[r] = 3.4e38f; bestI[r] = 0;
    #pragma unroll
    for (int t = 0; t < 4; ++t) {     // strict < : first occurrence wins ties
      if (s[t] < bestD[r]) { bestD[r] = s[t]; bestI[r] = cbase + t; }
    }
  }

  // in-wave argmin per row (tie -> lower index), then cross-wave via LDS
  #pragma unroll
  for (int r = 0; r < TM; ++r) {
    float v = bestD[r];
    int i = bestI[r];
    #pragma unroll
    for (int off = 32; off; off >>= 1) {
      float vd = __shfl_xor(v, off, 64);
      int vi = __shfl_xor(i, off, 64);
      if (vd < v || (vd == v && vi < i)) { v = vd; i = vi; }
    }
    if (lane == 0) { candD[r][wv] = v; candI[r][wv] = i; }
  }
  __syncthreads();
  if (tid < TM) {
    float bd = candD[tid][0];
    int bi = candI[tid][0];
    #pragma unroll
    for (int w = 1; w < 4; ++w) {     // ascending chunk = ascending index range;
      float d = candD[tid][w];        // strict < keeps lower index on exact tie
      int ii = candI[tid][w];
      if (d < bd) { bd = d; bi = ii; }
    }
    bcode[tid] = bi;
    idx_out[rowBase + tid] = (float)bi;
  }
  __syncthreads();

  // update: thread handles row tid>>4, dims (tid&15)*16 .. +15
  const int r = tid >> 4;
  const int dd = (tid & 15) * 16;
  const int code = bcode[r];
  const int row = rowBase + r;
  double lsum = 0.0;
  #pragma unroll
  for (int h = 0; h < 4; ++h) {
    const int d = dd + h * 4;
    const float4 ev = *(const float4*)(cb + (size_t)code * DIMD + d);
    const float4 rv = *(const float4*)(resid_r + (size_t)row * DIMD + d);
    // STE mirrored op-for-op — FROZEN (feeds next stage argmin):
    // t=fl(q-r); u=fl(r+t); r'=fl(r-u)
    float t0 = __fsub_rn(ev.x, rv.x), u0 = __fadd_rn(rv.x, t0);
    float t1 = __fsub_rn(ev.y, rv.y), u1 = __fadd_rn(rv.y, t1);
    float t2 = __fsub_rn(ev.z, rv.z), u2 = __fadd_rn(rv.z, t2);
    float t3 = __fsub_rn(ev.w, rv.w), u3 = __fadd_rn(rv.w, t3);
    *(float4*)(resid_w + (size_t)row * DIMD + d) =
        make_float4(__fsub_rn(rv.x, u0), __fsub_rn(rv.y, u1),
                    __fsub_rn(rv.z, u2), __fsub_rn(rv.w, u3));
    lsum += (double)__fmul_rn(t0, t0) + (double)__fmul_rn(t1, t1) +
            (double)__fmul_rn(t2, t2) + (double)__fmul_rn(t3, t3);
  }
  #pragma unroll
  for (int off = 32; off; off >>= 1) lsum += __shfl_xor(lsum, off, 64);
  if (lane == 0) lossW[wv] = lsum;
  __syncthreads();
  if (tid == 0) {
    double s = lossW[0] + lossW[1] + lossW[2] + lossW[3];
    atomicAdd(loss64, s);
  }
}

// out0 = x - resid_final (fp32): diff vs np STE-sum ~1e-5 << threshold 20.48
__global__ __launch_bounds__(256) void k_final(const float* __restrict__ x,
                                               const float* __restrict__ resid,
                                               const double* __restrict__ loss64,
                                               float* __restrict__ out_q,
                                               float* __restrict__ out_loss) {
  size_t i = (size_t)blockIdx.x * blockDim.x + threadIdx.x;
  const size_t n4 = (size_t)MM * DIMD / 4;
  const float4* xs = (const float4*)x;
  const float4* rd = (const float4*)resid;
  float4* q = (float4*)out_q;
  for (size_t p = i; p < n4; p += (size_t)gridDim.x * blockDim.x) {
    float4 a = xs[p], b = rd[p];
    q[p] = make_float4(__fsub_rn(a.x, b.x), __fsub_rn(a.y, b.y),
                       __fsub_rn(a.z, b.z), __fsub_rn(a.w, b.w));
  }
  if (i < QQ) out_loss[i] = (float)(loss64[i] * (1.0 / (double)((size_t)MM * DIMD)));
}

extern "C" void kernel_launch(void* const* d_in, const int* in_sizes, int n_in,
                              void* d_out, int out_size, void* d_ws, size_t ws_size,
                              hipStream_t stream) {
  const float* x = (const float*)d_in[0];        // [8,2048,256]
  const float* cb = (const float*)d_in[1];       // [4,1024,256]
  float* ws = (float*)d_ws;
  float* ET = ws;
  float* bK = ws + 1048576;
  float* resid = ws + 1052672;
  double* loss64 = (double*)(ws + 5246976);

  float* out = (float*)d_out;
  float* out_idx = out + (size_t)MM * DIMD;      // 4,194,304
  float* out_loss = out_idx + (size_t)QQ * MM;   // +65,536

  k_init<<<dim3(2048), dim3(256), 0, stream>>>(x, resid, loss64);
  k_prep<<<dim3(QQ * NE), dim3(64), 0, stream>>>(cb, ET);
  k_b<<<dim3(QQ * NE / 256), dim3(256), 0, stream>>>(cb, bK);
  for (int qi = 0; qi < QQ; ++qi) {
    k_stage<<<dim3(MM / TM), dim3(256), 0, stream>>>(
        ET + (size_t)qi * DIMD * NE, bK + (size_t)qi * NE,
        cb + (size_t)qi * NE * DIMD, resid, resid, loss64 + qi,
        out_idx + (size_t)qi * MM);
  }
  k_final<<<dim3(2048), dim3(256), 0, stream>>>(x, resid, loss64, out, out_loss);
}

// Round 8
// 654.320 us; speedup vs baseline: 1.1298x; 1.1298x over previous
//
#include <hip/hip_runtime.h>

// ResidualVQ: Q=4, N_EMBED=1024, DIM=256, B=8, S=2048 (fp32).
// out = [quantized 8*2048*256][indices-as-float 4*8*2048][losses 4]
//
// Bit-structural mirror of the numpy fp32 reference (verified R4-R7, idx exact):
//   dist = fl32( fl32(a - fl32(2*m)) + b ); a,b = AVX-512 pairwise sumsq;
//   m = ascending-d single-accumulator fp32 fma chain; first-occurrence argmin;
//   STE recursion op-for-op (feeds next stage's argmin -> FROZEN).
// R8 perf: 512-thread blocks (8 waves), TM=16 rows, 2 codes/lane ->
//   acc = 32 VGPR, launch_bounds(512,8) pins 64-VGPR budget (no AGPR churn,
//   32 waves/CU), ET L2 traffic halved to 4 MB/CU (~30us < 55us fmac floor).
#define QQ   4
#define NE   1024
#define DIMD 256
#define MM   16384
#define TM   16
#define NW   8      // waves per block

// ws layout (float offsets):
//  ET    [QQ][DIMD][NE] @ 0          (1,048,576)
//  bK    [QQ][NE]       @ 1,048,576  (4,096)
//  resid [MM][DIMD]     @ 1,052,672  (4,194,304)
//  loss64 double[QQ]    @ 5,246,976  (8B aligned)

// numpy (AVX-512 dispatch) pairwise sum of squares of 256 contiguous f32 — FROZEN
__device__ __forceinline__ float np_sumsq_256(const float* __restrict__ v) {
  float blk[2];
  #pragma unroll
  for (int bi = 0; bi < 2; ++bi) {
    const float* p = v + bi * 128;
    float w[16];
    #pragma unroll
    for (int L = 0; L < 16; ++L) {
      float s0 = __fmul_rn(p[0 * 16 + L], p[0 * 16 + L]);
      float s1 = __fmul_rn(p[1 * 16 + L], p[1 * 16 + L]);
      float s2 = __fmul_rn(p[2 * 16 + L], p[2 * 16 + L]);
      float s3 = __fmul_rn(p[3 * 16 + L], p[3 * 16 + L]);
      float s4 = __fmul_rn(p[4 * 16 + L], p[4 * 16 + L]);
      float s5 = __fmul_rn(p[5 * 16 + L], p[5 * 16 + L]);
      float s6 = __fmul_rn(p[6 * 16 + L], p[6 * 16 + L]);
      float s7 = __fmul_rn(p[7 * 16 + L], p[7 * 16 + L]);
      w[L] = __fadd_rn(__fadd_rn(__fadd_rn(s0, s1), __fadd_rn(s2, s3)),
                       __fadd_rn(__fadd_rn(s4, s5), __fadd_rn(s6, s7)));
    }
    float u[8], t[4], r2[2];
    #pragma unroll
    for (int L = 0; L < 8; ++L) u[L] = __fadd_rn(w[L], w[L + 8]);
    #pragma unroll
    for (int L = 0; L < 4; ++L) t[L] = __fadd_rn(u[L], u[L + 4]);
    #pragma unroll
    for (int L = 0; L < 2; ++L) r2[L] = __fadd_rn(t[L], t[L + 2]);
    blk[bi] = __fadd_rn(r2[0], r2[1]);
  }
  return __fadd_rn(blk[0], blk[1]);
}

__global__ __launch_bounds__(256) void k_init(const float* __restrict__ x,
                                              float* __restrict__ resid,
                                              double* __restrict__ loss64) {
  size_t i = (size_t)blockIdx.x * blockDim.x + threadIdx.x;
  const size_t n4 = (size_t)MM * DIMD / 4;
  const float4* xs = (const float4*)x;
  float4* rd = (float4*)resid;
  for (size_t p = i; p < n4; p += (size_t)gridDim.x * blockDim.x) rd[p] = xs[p];
  if (i < QQ) loss64[i] = 0.0;
}

// wave per (qi,code): transpose codebook row into ET[d][k]
__global__ __launch_bounds__(64) void k_prep(const float* __restrict__ cb,
                                             float* __restrict__ ET) {
  int b = blockIdx.x;                 // qi*NE + k
  int qi = b >> 10, k = b & (NE - 1);
  int lane = threadIdx.x;
  const float* row = cb + ((size_t)qi * NE + k) * DIMD;
  float4 v = *(const float4*)(row + lane * 4);
  float* et = ET + (size_t)qi * DIMD * NE + k;
  int d = lane * 4;
  et[(size_t)(d + 0) * NE] = v.x;
  et[(size_t)(d + 1) * NE] = v.y;
  et[(size_t)(d + 2) * NE] = v.z;
  et[(size_t)(d + 3) * NE] = v.w;
}

__global__ __launch_bounds__(256) void k_b(const float* __restrict__ cb,
                                           float* __restrict__ bK) {
  int k = blockIdx.x * 256 + threadIdx.x;
  bK[k] = np_sumsq_256(cb + (size_t)k * DIMD);
}

// 512 threads = 8 waves; block handles TM=16 rows; wave w covers codes
// [w*128, (w+1)*128), lane owns 2 codes. x loads wave-uniform (s_load path).
__global__ __launch_bounds__(512, 8) void k_stage(
    const float* __restrict__ ET,      // [DIMD][NE] for qi
    const float* __restrict__ bK,      // [NE] for qi
    const float* __restrict__ cb,      // [NE][DIMD] for qi
    const float* __restrict__ resid_r, // == resid
    float* __restrict__ resid_w,       // == resid
    double* __restrict__ loss64,       // &loss64[qi]
    float* __restrict__ idx_out) {     // [MM] floats
  __shared__ float av_s[TM];
  __shared__ float candD[TM][NW];
  __shared__ int   candI[TM][NW];
  __shared__ int   bcode[TM];
  __shared__ double lossW[NW];

  const int tid  = threadIdx.x;
  const int lane = tid & 63;
  const int wv   = tid >> 6;
  const int rowBase = blockIdx.x * TM;

  // a_m for this block's rows — FROZEN np pairwise sumsq
  if (tid < TM) av_s[tid] = np_sumsq_256(resid_r + (size_t)(rowBase + tid) * DIMD);
  __syncthreads();

  const int cbase = wv * 128 + lane * 2;   // this wave's chunk, lane's 2 codes

  float2 acc[TM];                          // 32 VGPRs
  #pragma unroll
  for (int r = 0; r < TM; ++r) acc[r] = make_float2(0.f, 0.f);

  // m: single-accumulator fp32 fma chain, strictly ascending d per code — FROZEN
  for (int d0 = 0; d0 < DIMD; d0 += 4) {
    float2 e[4];
    #pragma unroll
    for (int j = 0; j < 4; ++j)
      e[j] = *(const float2*)(ET + (size_t)(d0 + j) * NE + cbase);
    // two 8-row groups to cap live scalar regs (x loads wave-uniform -> s_load)
    #pragma unroll
    for (int g = 0; g < 2; ++g) {
      float4 xr[8];
      #pragma unroll
      for (int r = 0; r < 8; ++r)
        xr[r] = *(const float4*)(resid_r + (size_t)(rowBase + g * 8 + r) * DIMD + d0);
      #pragma unroll
      for (int j = 0; j < 4; ++j) {
        #pragma unroll
        for (int r = 0; r < 8; ++r) {
          float xv = (j == 0) ? xr[r].x : (j == 1) ? xr[r].y : (j == 2) ? xr[r].z : xr[r].w;
          float2& a = acc[g * 8 + r];
          a.x = fmaf(xv, e[j].x, a.x);
          a.y = fmaf(xv, e[j].y, a.y);
        }
      }
    }
  }

  float2 bv = *(const float2*)(bK + cbase);
  float bestD[TM];
  int bestI[TM];
  #pragma unroll
  for (int r = 0; r < TM; ++r) {
    const float av = av_s[r];
    float s0 = __fadd_rn(__fsub_rn(av, __fmul_rn(2.0f, acc[r].x)), bv.x);
    float s1 = __fadd_rn(__fsub_rn(av, __fmul_rn(2.0f, acc[r].y)), bv.y);
    // strict < : first occurrence wins ties
    bestD[r] = s0; bestI[r] = cbase;
    if (s1 < bestD[r]) { bestD[r] = s1; bestI[r] = cbase + 1; }
  }

  // in-wave argmin per row (tie -> lower index), then cross-wave via LDS
  #pragma unroll
  for (int r = 0; r < TM; ++r) {
    float v = bestD[r];
    int i = bestI[r];
    #pragma unroll
    for (int off = 32; off; off >>= 1) {
      float vd = __shfl_xor(v, off, 64);
      int vi = __shfl_xor(i, off, 64);
      if (vd < v || (vd == v && vi < i)) { v = vd; i = vi; }
    }
    if (lane == 0) { candD[r][wv] = v; candI[r][wv] = i; }
  }
  __syncthreads();
  if (tid < TM) {
    float bd = candD[tid][0];
    int bi = candI[tid][0];
    #pragma unroll
    for (int w = 1; w < NW; ++w) {    // ascending chunk = ascending index range;
      float d = candD[tid][w];        // strict < keeps lower index on exact tie
      int ii = candI[tid][w];
      if (d < bd) { bd = d; bi = ii; }
    }
    bcode[tid] = bi;
    idx_out[rowBase + tid] = (float)bi;
  }
  __syncthreads();

  // update: thread handles row tid>>5, dims (tid&31)*8 .. +7
  const int r = tid >> 5;
  const int dd = (tid & 31) * 8;
  const int code = bcode[r];
  const int row = rowBase + r;
  double lsum = 0.0;
  #pragma unroll
  for (int h = 0; h < 2; ++h) {
    const int d = dd + h * 4;
    const float4 ev = *(const float4*)(cb + (size_t)code * DIMD + d);
    const float4 rv = *(const float4*)(resid_r + (size_t)row * DIMD + d);
    // STE mirrored op-for-op — FROZEN (feeds next stage argmin):
    // t=fl(q-r); u=fl(r+t); r'=fl(r-u)
    float t0 = __fsub_rn(ev.x, rv.x), u0 = __fadd_rn(rv.x, t0);
    float t1 = __fsub_rn(ev.y, rv.y), u1 = __fadd_rn(rv.y, t1);
    float t2 = __fsub_rn(ev.z, rv.z), u2 = __fadd_rn(rv.z, t2);
    float t3 = __fsub_rn(ev.w, rv.w), u3 = __fadd_rn(rv.w, t3);
    *(float4*)(resid_w + (size_t)row * DIMD + d) =
        make_float4(__fsub_rn(rv.x, u0), __fsub_rn(rv.y, u1),
                    __fsub_rn(rv.z, u2), __fsub_rn(rv.w, u3));
    lsum += (double)__fmul_rn(t0, t0) + (double)__fmul_rn(t1, t1) +
            (double)__fmul_rn(t2, t2) + (double)__fmul_rn(t3, t3);
  }
  #pragma unroll
  for (int off = 32; off; off >>= 1) lsum += __shfl_xor(lsum, off, 64);
  if (lane == 0) lossW[wv] = lsum;
  __syncthreads();
  if (tid == 0) {
    double s = 0.0;
    #pragma unroll
    for (int w = 0; w < NW; ++w) s += lossW[w];
    atomicAdd(loss64, s);
  }
}

// out0 = x - resid_final (fp32): diff vs np STE-sum ~1e-5 << threshold 20.48
__global__ __launch_bounds__(256) void k_final(const float* __restrict__ x,
                                               const float* __restrict__ resid,
                                               const double* __restrict__ loss64,
                                               float* __restrict__ out_q,
                                               float* __restrict__ out_loss) {
  size_t i = (size_t)blockIdx.x * blockDim.x + threadIdx.x;
  const size_t n4 = (size_t)MM * DIMD / 4;
  const float4* xs = (const float4*)x;
  const float4* rd = (const float4*)resid;
  float4* q = (float4*)out_q;
  for (size_t p = i; p < n4; p += (size_t)gridDim.x * blockDim.x) {
    float4 a = xs[p], b = rd[p];
    q[p] = make_float4(__fsub_rn(a.x, b.x), __fsub_rn(a.y, b.y),
                       __fsub_rn(a.z, b.z), __fsub_rn(a.w, b.w));
  }
  if (i < QQ) out_loss[i] = (float)(loss64[i] * (1.0 / (double)((size_t)MM * DIMD)));
}

extern "C" void kernel_launch(void* const* d_in, const int* in_sizes, int n_in,
                              void* d_out, int out_size, void* d_ws, size_t ws_size,
                              hipStream_t stream) {
  const float* x = (const float*)d_in[0];        // [8,2048,256]
  const float* cb = (const float*)d_in[1];       // [4,1024,256]
  float* ws = (float*)d_ws;
  float* ET = ws;
  float* bK = ws + 1048576;
  float* resid = ws + 1052672;
  double* loss64 = (double*)(ws + 5246976);

  float* out = (float*)d_out;
  float* out_idx = out + (size_t)MM * DIMD;      // 4,194,304
  float* out_loss = out_idx + (size_t)QQ * MM;   // +65,536

  k_init<<<dim3(2048), dim3(256), 0, stream>>>(x, resid, loss64);
  k_prep<<<dim3(QQ * NE), dim3(64), 0, stream>>>(cb, ET);
  k_b<<<dim3(QQ * NE / 256), dim3(256), 0, stream>>>(cb, bK);
  for (int qi = 0; qi < QQ; ++qi) {
    k_stage<<<dim3(MM / TM), dim3(512), 0, stream>>>(
        ET + (size_t)qi * DIMD * NE, bK + (size_t)qi * NE,
        cb + (size_t)qi * NE * DIMD, resid, resid, loss64 + qi,
        out_idx + (size_t)qi * MM);
  }
  k_final<<<dim3(2048), dim3(256), 0, stream>>>(x, resid, loss64, out, out_loss);
}